// Round 2
// baseline (380.469 us; speedup 1.0000x reference)
//
#include <hip/hip_runtime.h>
#include <stdint.h>

typedef __attribute__((ext_vector_type(8))) short bf16x8;
typedef __attribute__((ext_vector_type(4))) float f32x4;

#define MFMA16(A, B, C) __builtin_amdgcn_mfma_f32_16x16x32_bf16(A, B, C, 0, 0, 0)

static __device__ __forceinline__ unsigned short f2bf(float f) {
  uint32_t u = __float_as_uint(f);
  u = (u + 0x7fffu + ((u >> 16) & 1u)) >> 16;
  return (unsigned short)u;
}

static __device__ __forceinline__ bf16x8 pack8(float4 a, float4 b) {
  bf16x8 r;
  r[0] = (short)f2bf(a.x); r[1] = (short)f2bf(a.y);
  r[2] = (short)f2bf(a.z); r[3] = (short)f2bf(a.w);
  r[4] = (short)f2bf(b.x); r[5] = (short)f2bf(b.y);
  r[6] = (short)f2bf(b.z); r[7] = (short)f2bf(b.w);
  return r;
}

// ---------------- K0: weight prep (f32 -> bf16, Wsr transposed to [o][s*128+c]) ----------
#define TOT_PREP (16384 + 16384 + 32768 + 1048576)
__global__ void prep_kernel(const float* __restrict__ Wq, const float* __restrict__ Wkv,
                            const float* __restrict__ Wp, const float* __restrict__ Wsr,
                            unsigned short* __restrict__ Wq_bf, unsigned short* __restrict__ Wkv_bf,
                            unsigned short* __restrict__ Wp_bf, unsigned short* __restrict__ Wsrt_bf) {
  int idx = blockIdx.x * 256 + threadIdx.x;
  if (idx >= TOT_PREP) return;
  if (idx < 16384) { Wq_bf[idx] = f2bf(Wq[idx]); return; }
  idx -= 16384;
  if (idx < 16384) { Wp_bf[idx] = f2bf(Wp[idx]); return; }
  idx -= 16384;
  if (idx < 32768) { Wkv_bf[idx] = f2bf(Wkv[idx]); return; }
  idx -= 32768;
  // Wsr: [o][c][kh][kw] -> Wsrt: [o][s*128+c], s = kh*8+kw
  int o = idx >> 13, r13 = idx & 8191, s = r13 >> 7, c = r13 & 127;
  Wsrt_bf[idx] = f2bf(Wsr[(o << 13) + (c << 6) + s]);
}

// ---------------- K1: conv as split-K patch-GEMM. grid (128 patch-tiles, 4 K-splits) -----
// Each block: 16 patches x 128 outputs over K=2048 (2 kh planes); 4 waves split K 4-ways.
// Writes f32 partials to scratch[ks][2048][128].
__global__ __launch_bounds__(256, 4) void conv_split_kernel(
    const float* __restrict__ x, const unsigned short* __restrict__ Wsrt_bf,
    float* __restrict__ scratch) {
  const int tid = threadIdx.x;
  const int wave = tid >> 6, l = tid & 63, lg = l >> 4, lr = l & 15;
  const int pt = blockIdx.x;          // patch tile (16 patches)
  const int ks = blockIdx.y;          // K split (2048 each)

  __shared__ float red[4][16][128];

  const f32x4 zr = {0.f, 0.f, 0.f, 0.f};
  f32x4 acc[8];
#pragma unroll
  for (int ct = 0; ct < 8; ++ct) acc[ct] = zr;

  const int p = pt * 16 + lr;
  const int b = p >> 8, ii = (p >> 4) & 15, jj = p & 15;
  const int kbase = ks * 2048 + wave * 512;

  for (int kt = 0; kt < 16; ++kt) {
    const int k = kbase + kt * 32;
    const int s = k >> 7, c0 = k & 127;
    const int kh = s >> 3, kw = s & 7;
    const float4* xp =
        (const float4*)(x + ((size_t)((b * 128 + ii * 8 + kh) * 128 + jj * 8 + kw)) * 128 + c0 + lg * 8);
    bf16x8 af = pack8(xp[0], xp[1]);
    const unsigned short* wb = Wsrt_bf + k + lg * 8;
#pragma unroll
    for (int ct = 0; ct < 8; ++ct) {
      bf16x8 bfr = *(const bf16x8*)(wb + (ct * 16 + lr) * 8192);
      acc[ct] = MFMA16(af, bfr, acc[ct]);
    }
  }

#pragma unroll
  for (int ct = 0; ct < 8; ++ct)
#pragma unroll
    for (int r = 0; r < 4; ++r)
      red[wave][lg * 4 + r][ct * 16 + lr] = acc[ct][r];
  __syncthreads();

#pragma unroll
  for (int rr = 0; rr < 8; ++rr) {
    int idx = rr * 256 + tid;
    int row = idx >> 7, c = idx & 127;
    float v = red[0][row][c] + red[1][row][c] + red[2][row][c] + red[3][row][c];
    scratch[((size_t)(ks * 2048 + pt * 16 + row)) * 128 + c] = v;
  }
}

// ---------------- K2: sum partials + bias + LayerNorm + KV projection --------------------
// grid: 128 blocks x 16 rows.
__global__ __launch_bounds__(256, 2) void ln_kv_kernel(
    const float* __restrict__ scratch, const float* __restrict__ bsr,
    const float* __restrict__ gamma, const float* __restrict__ beta,
    const unsigned short* __restrict__ Wkv_bf, const float* __restrict__ bkv,
    unsigned short* __restrict__ K_bf, unsigned short* __restrict__ Vt_bf) {
  const int tid = threadIdx.x;
  const int wave = tid >> 6, l = tid & 63, lg = l >> 4, lr = l & 15;
  const int blk = blockIdx.x;

  __shared__ unsigned short lns[16][136];

  // sum 4 K-splits + bias, LN per row (16 threads per row, 8 c each)
  {
    const int row = tid >> 4, c0 = (tid & 15) * 8;
    const int p = blk * 16 + row;
    float vals[8];
#pragma unroll
    for (int cc = 0; cc < 8; ++cc) vals[cc] = bsr[c0 + cc];
#pragma unroll
    for (int ksp = 0; ksp < 4; ++ksp) {
      const float4* sp = (const float4*)(scratch + ((size_t)(ksp * 2048 + p)) * 128 + c0);
      float4 a = sp[0], bb = sp[1];
      vals[0] += a.x; vals[1] += a.y; vals[2] += a.z; vals[3] += a.w;
      vals[4] += bb.x; vals[5] += bb.y; vals[6] += bb.z; vals[7] += bb.w;
    }
    float s1 = 0.f, s2 = 0.f;
#pragma unroll
    for (int cc = 0; cc < 8; ++cc) { s1 += vals[cc]; s2 += vals[cc] * vals[cc]; }
#pragma unroll
    for (int msk = 1; msk < 16; msk <<= 1) { s1 += __shfl_xor(s1, msk); s2 += __shfl_xor(s2, msk); }
    float mean = s1 * (1.f / 128.f);
    float var = s2 * (1.f / 128.f) - mean * mean;
    float rstd = rsqrtf(var + 1e-5f);
#pragma unroll
    for (int cc = 0; cc < 8; ++cc) {
      int c = c0 + cc;
      lns[row][c] = f2bf((vals[cc] - mean) * rstd * gamma[c] + beta[c]);
    }
  }
  __syncthreads();

  // KV projection: [16 rows] x [256 o2], K=128. wave handles 4 o2-tiles.
  const f32x4 zr = {0.f, 0.f, 0.f, 0.f};
  f32x4 kv[4];
#pragma unroll
  for (int q = 0; q < 4; ++q) kv[q] = zr;
#pragma unroll
  for (int kt = 0; kt < 4; ++kt) {
    bf16x8 af = *(const bf16x8*)(&lns[lr][kt * 32 + lg * 8]);
#pragma unroll
    for (int q = 0; q < 4; ++q) {
      bf16x8 bfr = *(const bf16x8*)(Wkv_bf + ((wave * 4 + q) * 16 + lr) * 128 + kt * 32 + lg * 8);
      kv[q] = MFMA16(af, bfr, kv[q]);
    }
  }
#pragma unroll
  for (int q = 0; q < 4; ++q)
#pragma unroll
    for (int r = 0; r < 4; ++r) {
      int o2 = (wave * 4 + q) * 16 + lr;
      int mrow = lg * 4 + r;
      int pp = blk * 16 + mrow;
      int bb = pp >> 8, mm = pp & 255;
      float val = kv[q][r] + bkv[o2];
      unsigned short hv = f2bf(val);
      if (o2 < 128) {                       // K: [b][h][m][d]
        int h = o2 >> 6, d = o2 & 63;
        K_bf[(((size_t)(bb * 2 + h)) * 256 + mm) * 64 + d] = hv;
      } else {                              // V transposed: [b][h][d][m]
        int o3 = o2 - 128, h = o3 >> 6, d = o3 & 63;
        Vt_bf[(((size_t)(bb * 2 + h)) * 64 + d) * 256 + mm] = hv;
      }
    }
}

// ---------------- K3: fused Qproj + attention + output projection ------------------------
// grid: (256 n-tiles of 64 rows, 8 batches), 256 threads, ~52 KB LDS -> 3 blocks/CU.
// K/V read directly from global (L1/L2-resident: 512 KB total).
__global__ __launch_bounds__(256, 3) void attn_kernel(
    const float* __restrict__ x, const float* __restrict__ bq, const float* __restrict__ bp,
    const unsigned short* __restrict__ Wq_bf, const unsigned short* __restrict__ Wp_bf,
    const unsigned short* __restrict__ K_bf, const unsigned short* __restrict__ Vt_bf,
    float* __restrict__ out) {
  const int tid = threadIdx.x;
  const int wave = tid >> 6, l = tid & 63, lg = l >> 4, lr = l & 15;
  const int b = blockIdx.y;
  const int n0 = blockIdx.x * 64;

  __shared__ unsigned short Qs[64][136];    // 17408 B
  __shared__ unsigned short Ps[4][16][272]; // 34816 B; reused as O [64][136] later

  const f32x4 zr = {0.f, 0.f, 0.f, 0.f};

  // ---- Q projection: wave w computes rows w*16 .. w*16+15 ----
  {
    f32x4 qa[8];
#pragma unroll
    for (int ct = 0; ct < 8; ++ct) qa[ct] = zr;
#pragma unroll
    for (int kt = 0; kt < 4; ++kt) {
      const float4* xp =
          (const float4*)(x + ((size_t)(b * 16384 + n0 + wave * 16 + lr)) * 128 + kt * 32 + lg * 8);
      bf16x8 af = pack8(xp[0], xp[1]);
#pragma unroll
      for (int ct = 0; ct < 8; ++ct) {
        bf16x8 bfr = *(const bf16x8*)(Wq_bf + (ct * 16 + lr) * 128 + kt * 32 + lg * 8);
        qa[ct] = MFMA16(af, bfr, qa[ct]);
      }
    }
#pragma unroll
    for (int ct = 0; ct < 8; ++ct)
#pragma unroll
      for (int r = 0; r < 4; ++r) {
        int row = wave * 16 + lg * 4 + r;
        int col = ct * 16 + lr;
        Qs[row][col] = f2bf(qa[ct][r] + bq[col]);
      }
  }
  __syncthreads();

  f32x4 oacc[2][4];
#pragma unroll
  for (int h2 = 0; h2 < 2; ++h2)
#pragma unroll
    for (int dt = 0; dt < 4; ++dt) oacc[h2][dt] = zr;

  for (int h = 0; h < 2; ++h) {
    // S^T = mfma(K, Q): per wave [256 m][16 n]; lane owns n = lr, m = mt*16+lg*4+r.
    const unsigned short* kbase = K_bf + ((size_t)(b * 2 + h)) * 256 * 64;
    f32x4 sacc[16];
#pragma unroll
    for (int mt = 0; mt < 16; ++mt) sacc[mt] = zr;
#pragma unroll
    for (int d0 = 0; d0 < 64; d0 += 32) {
      bf16x8 qf = *(const bf16x8*)(&Qs[wave * 16 + lr][h * 64 + d0 + lg * 8]);
#pragma unroll
      for (int mt = 0; mt < 16; ++mt) {
        bf16x8 kf = *(const bf16x8*)(kbase + (mt * 16 + lr) * 64 + d0 + lg * 8);
        sacc[mt] = MFMA16(kf, qf, sacc[mt]);
      }
    }
    // softmax over m=256 for this lane's n
    float mx = -1e30f;
#pragma unroll
    for (int mt = 0; mt < 16; ++mt)
#pragma unroll
      for (int r = 0; r < 4; ++r) mx = fmaxf(mx, sacc[mt][r]);
    mx = fmaxf(mx, __shfl_xor(mx, 16));
    mx = fmaxf(mx, __shfl_xor(mx, 32));
    float sum = 0.f;
#pragma unroll
    for (int mt = 0; mt < 16; ++mt)
#pragma unroll
      for (int r = 0; r < 4; ++r) {
        float pv = __expf((sacc[mt][r] - mx) * 0.125f);
        sacc[mt][r] = pv; sum += pv;
      }
    sum += __shfl_xor(sum, 16);
    sum += __shfl_xor(sum, 32);
    float inv = 1.f / sum;
#pragma unroll
    for (int mt = 0; mt < 16; ++mt) {
      unsigned int w0 = (unsigned int)f2bf(sacc[mt][0] * inv) | ((unsigned int)f2bf(sacc[mt][1] * inv) << 16);
      unsigned int w1 = (unsigned int)f2bf(sacc[mt][2] * inv) | ((unsigned int)f2bf(sacc[mt][3] * inv) << 16);
      uint2 pw; pw.x = w0; pw.y = w1;
      *(uint2*)(&Ps[wave][lr][mt * 16 + lg * 4]) = pw;   // P[n_local=lr][m] (wave-private)
    }

    // PV: O[16 n][64 d] += P @ V_h  (V^T fragments from global)
    const unsigned short* vbase = Vt_bf + ((size_t)(b * 2 + h)) * 64 * 256;
#pragma unroll
    for (int ki = 0; ki < 8; ++ki) {
      bf16x8 pf = *(const bf16x8*)(&Ps[wave][lr][ki * 32 + lg * 8]);
#pragma unroll
      for (int dt = 0; dt < 4; ++dt) {
        bf16x8 vf = *(const bf16x8*)(vbase + (dt * 16 + lr) * 256 + ki * 32 + lg * 8);
        oacc[h][dt] = MFMA16(pf, vf, oacc[h][dt]);
      }
    }
  }  // head

  __syncthreads();  // all waves done with Ps before overwriting region with O
  unsigned short* Op = &Ps[0][0][0];  // [64][136]
#pragma unroll
  for (int h = 0; h < 2; ++h)
#pragma unroll
    for (int dt = 0; dt < 4; ++dt)
#pragma unroll
      for (int r = 0; r < 4; ++r) {
        int row = wave * 16 + lg * 4 + r;
        int col = h * 64 + dt * 16 + lr;
        Op[row * 136 + col] = f2bf(oacc[h][dt][r]);
      }
  // out-proj reads only this wave's own rows -> no extra barrier needed

  f32x4 yacc[8];
#pragma unroll
  for (int ct = 0; ct < 8; ++ct) yacc[ct] = zr;
#pragma unroll
  for (int kt = 0; kt < 4; ++kt) {
    bf16x8 af = *(const bf16x8*)(&Op[(wave * 16 + lr) * 136 + kt * 32 + lg * 8]);
#pragma unroll
    for (int ct = 0; ct < 8; ++ct) {
      bf16x8 bfr = *(const bf16x8*)(Wp_bf + (ct * 16 + lr) * 128 + kt * 32 + lg * 8);
      yacc[ct] = MFMA16(af, bfr, yacc[ct]);
    }
  }
#pragma unroll
  for (int ct = 0; ct < 8; ++ct)
#pragma unroll
    for (int r = 0; r < 4; ++r) {
      int n = n0 + wave * 16 + lg * 4 + r;
      int o = ct * 16 + lr;
      out[((size_t)(b * 16384 + n)) * 128 + o] = yacc[ct][r] + bp[o];
    }
}

extern "C" void kernel_launch(void* const* d_in, const int* in_sizes, int n_in,
                              void* d_out, int out_size, void* d_ws, size_t ws_size,
                              hipStream_t stream) {
  const float* x = (const float*)d_in[0];
  const float* Wq = (const float*)d_in[3];
  const float* bq = (const float*)d_in[4];
  const float* Wkv = (const float*)d_in[5];
  const float* bkv = (const float*)d_in[6];
  const float* Wp = (const float*)d_in[7];
  const float* bp = (const float*)d_in[8];
  const float* Wsr = (const float*)d_in[9];
  const float* bsr = (const float*)d_in[10];
  const float* gamma = (const float*)d_in[11];
  const float* beta = (const float*)d_in[12];
  float* out = (float*)d_out;

  unsigned short* ws = (unsigned short*)d_ws;
  unsigned short* Wq_bf = ws;                 // 16384
  unsigned short* Wp_bf = ws + 16384;         // 16384
  unsigned short* Wkv_bf = ws + 32768;        // 32768
  unsigned short* Wsrt_bf = ws + 65536;       // 1048576
  unsigned short* K_bf = ws + 1114112;        // 262144  [8][2][256][64]
  unsigned short* Vt_bf = ws + 1376256;       // 262144  [8][2][64][256]
  float* scratch = (float*)(ws + 1638400);    // 4*2048*128 f32 = 4 MB partials

  prep_kernel<<<(TOT_PREP + 255) / 256, 256, 0, stream>>>(Wq, Wkv, Wp, Wsr, Wq_bf, Wkv_bf, Wp_bf, Wsrt_bf);
  conv_split_kernel<<<dim3(128, 4), 256, 0, stream>>>(x, Wsrt_bf, scratch);
  ln_kv_kernel<<<128, 256, 0, stream>>>(scratch, bsr, gamma, beta, Wkv_bf, bkv, K_bf, Vt_bf);
  attn_kernel<<<dim3(256, 8), 256, 0, stream>>>(x, bq, bp, Wq_bf, Wp_bf, K_bf, Vt_bf, out);
}

// Round 3
// 286.359 us; speedup vs baseline: 1.3286x; 1.3286x over previous
//
#include <hip/hip_runtime.h>
#include <stdint.h>

typedef __attribute__((ext_vector_type(8))) short bf16x8;
typedef __attribute__((ext_vector_type(4))) float f32x4;

#define MFMA16(A, B, C) __builtin_amdgcn_mfma_f32_16x16x32_bf16(A, B, C, 0, 0, 0)

static __device__ __forceinline__ unsigned short f2bf(float f) {
  uint32_t u = __float_as_uint(f);
  u = (u + 0x7fffu + ((u >> 16) & 1u)) >> 16;
  return (unsigned short)u;
}

static __device__ __forceinline__ bf16x8 pack8(float4 a, float4 b) {
  bf16x8 r;
  r[0] = (short)f2bf(a.x); r[1] = (short)f2bf(a.y);
  r[2] = (short)f2bf(a.z); r[3] = (short)f2bf(a.w);
  r[4] = (short)f2bf(b.x); r[5] = (short)f2bf(b.y);
  r[6] = (short)f2bf(b.z); r[7] = (short)f2bf(b.w);
  return r;
}

// ======== K0: xcast + weight prep ========================================================
// blocks [0,8192): x f32 -> bf16 into TWO frag-major layouts (x2 for attn, x3 for conv)
// blocks [8192,8256): Wsr -> W2sr frag-major
// blocks [8256,8512): Wq/Wp/Wkv -> frag-major
__global__ __launch_bounds__(256) void xcast_prep_kernel(
    const float* __restrict__ x, const float* __restrict__ Wq, const float* __restrict__ Wkv,
    const float* __restrict__ Wp, const float* __restrict__ Wsr,
    unsigned short* __restrict__ x2, unsigned short* __restrict__ x3,
    unsigned short* __restrict__ Wq2, unsigned short* __restrict__ Wkv2,
    unsigned short* __restrict__ Wp2, unsigned short* __restrict__ W2sr) {
  const int bid = blockIdx.x;
  const int tid = threadIdx.x;
  if (bid < 8192) {
    // x: 16M elems, 8 per thread, fully coalesced read
    size_t t = (size_t)bid * 256 + tid;      // < 2097152
    const float4* xp = (const float4*)(x + t * 8);
    bf16x8 v = pack8(xp[0], xp[1]);
    int n_all = (int)(t >> 4);
    int b = n_all >> 14, n = n_all & 16383;
    int c8 = (int)(t & 15);
    int c5 = c8 >> 2, c31 = (c8 & 3) * 8;
    // x2: [(b)][(n>>4)*4 + c5][ (n&15)*32 + c31 ]  (512-elem chunks)
    size_t i2 = (size_t)b * 2097152 + ((size_t)((n >> 4) * 4 + c5)) * 512 + (n & 15) * 32 + c31;
    *(bf16x8*)(x2 + i2) = v;
    // x3: [(b*128+y)][kw*4 + c5][ jj*32 + c31 ]
    int y = n >> 7, xx = n & 127, jj = xx >> 3, kw = xx & 7;
    size_t i3 = (size_t)(b * 128 + y) * 16384 + ((size_t)(kw * 4 + c5)) * 512 + jj * 32 + c31;
    *(bf16x8*)(x3 + i3) = v;
    return;
  }
  if (bid < 8256) {
    // Wsr [o][c][s] -> W2sr[((s*4 + c>>5)*128 + o)*32 + (c&31)]
    int t = (bid - 8192) * 256 + tid;        // < 16384
    int o = t >> 7, c = t & 127;
    const float4* wp = (const float4*)(Wsr + (size_t)t * 64);
#pragma unroll
    for (int s4 = 0; s4 < 16; ++s4) {
      float4 v = wp[s4];
#pragma unroll
      for (int e = 0; e < 4; ++e) {
        int s = s4 * 4 + e;
        float f = (e == 0) ? v.x : (e == 1) ? v.y : (e == 2) ? v.z : v.w;
        W2sr[(size_t)((s * 4 + (c >> 5)) * 128 + o) * 32 + (c & 31)] = f2bf(f);
      }
    }
    return;
  }
  {
    int t = (bid - 8256) * 256 + tid;        // < 65536
    if (t < 16384) {
      int o = t >> 7, c = t & 127;
      Wq2[((c >> 5) * 128 + o) * 32 + (c & 31)] = f2bf(Wq[t]);
    } else if (t < 32768) {
      int u = t - 16384;
      int o = u >> 7, c = u & 127;
      Wp2[((c >> 5) * 128 + o) * 32 + (c & 31)] = f2bf(Wp[u]);
    } else {
      int u = t - 32768;
      int o = u >> 7, c = u & 127;
      Wkv2[((c >> 5) * 256 + o) * 32 + (c & 31)] = f2bf(Wkv[u]);
    }
  }
}

// ======== K1: conv split-K patch-GEMM, all-contiguous frag loads =========================
// grid (128 patch-tiles, 4 K-splits), 256 thr. Writes f32 partials scratch[ks][2048][128].
__global__ __launch_bounds__(256, 4) void conv_split_kernel(
    const unsigned short* __restrict__ x3, const unsigned short* __restrict__ W2sr,
    float* __restrict__ scratch) {
  const int tid = threadIdx.x;
  const int wave = tid >> 6, l = tid & 63, lg = l >> 4, lr = l & 15;
  const int pt = blockIdx.x;
  const int ks = blockIdx.y;

  __shared__ float red[4][16][128];

  const f32x4 zr = {0.f, 0.f, 0.f, 0.f};
  f32x4 acc[8];
#pragma unroll
  for (int ct = 0; ct < 8; ++ct) acc[ct] = zr;

  const int p = pt * 16;                     // 16 consecutive patches; jj = lr
  const int b = p >> 8, ii = (p >> 4) & 15;

  for (int kt = 0; kt < 16; ++kt) {
    const int k = ks * 2048 + wave * 512 + kt * 32;
    const int s = k >> 7, c0t = (k >> 5) & 3;
    const int kh = s >> 3, kw = s & 7, y = ii * 8 + kh;
    bf16x8 af = *(const bf16x8*)(x3 + (size_t)(b * 128 + y) * 16384 + (kw * 4 + c0t) * 512 + lr * 32 + lg * 8);
    const unsigned short* wb = W2sr + (size_t)(k >> 5) * 4096;
#pragma unroll
    for (int ct = 0; ct < 8; ++ct) {
      bf16x8 bfr = *(const bf16x8*)(wb + (ct * 16 + lr) * 32 + lg * 8);
      acc[ct] = MFMA16(af, bfr, acc[ct]);
    }
  }

#pragma unroll
  for (int ct = 0; ct < 8; ++ct)
#pragma unroll
    for (int r = 0; r < 4; ++r)
      red[wave][lg * 4 + r][ct * 16 + lr] = acc[ct][r];
  __syncthreads();

#pragma unroll
  for (int rr = 0; rr < 8; ++rr) {
    int idx = rr * 256 + tid;
    int row = idx >> 7, c = idx & 127;
    float v = red[0][row][c] + red[1][row][c] + red[2][row][c] + red[3][row][c];
    scratch[((size_t)(ks * 2048 + pt * 16 + row)) * 128 + c] = v;
  }
}

// ======== K2: sum partials + bias + LayerNorm + KV proj (frag-major K2/V2 out) ===========
__global__ __launch_bounds__(256, 2) void ln_kv_kernel(
    const float* __restrict__ scratch, const float* __restrict__ bsr,
    const float* __restrict__ gamma, const float* __restrict__ beta,
    const unsigned short* __restrict__ Wkv2, const float* __restrict__ bkv,
    unsigned short* __restrict__ K2, unsigned short* __restrict__ V2) {
  const int tid = threadIdx.x;
  const int wave = tid >> 6, l = tid & 63, lg = l >> 4, lr = l & 15;
  const int blk = blockIdx.x;

  __shared__ unsigned short lns[16][136];

  {
    const int row = tid >> 4, c0 = (tid & 15) * 8;
    const int p = blk * 16 + row;
    float vals[8];
#pragma unroll
    for (int cc = 0; cc < 8; ++cc) vals[cc] = bsr[c0 + cc];
#pragma unroll
    for (int ksp = 0; ksp < 4; ++ksp) {
      const float4* sp = (const float4*)(scratch + ((size_t)(ksp * 2048 + p)) * 128 + c0);
      float4 a = sp[0], bb = sp[1];
      vals[0] += a.x; vals[1] += a.y; vals[2] += a.z; vals[3] += a.w;
      vals[4] += bb.x; vals[5] += bb.y; vals[6] += bb.z; vals[7] += bb.w;
    }
    float s1 = 0.f, s2 = 0.f;
#pragma unroll
    for (int cc = 0; cc < 8; ++cc) { s1 += vals[cc]; s2 += vals[cc] * vals[cc]; }
#pragma unroll
    for (int msk = 1; msk < 16; msk <<= 1) { s1 += __shfl_xor(s1, msk); s2 += __shfl_xor(s2, msk); }
    float mean = s1 * (1.f / 128.f);
    float var = s2 * (1.f / 128.f) - mean * mean;
    float rstd = rsqrtf(var + 1e-5f);
#pragma unroll
    for (int cc = 0; cc < 8; ++cc) {
      int c = c0 + cc;
      lns[row][c] = f2bf((vals[cc] - mean) * rstd * gamma[c] + beta[c]);
    }
  }
  __syncthreads();

  const f32x4 zr = {0.f, 0.f, 0.f, 0.f};
  f32x4 kv[4];
#pragma unroll
  for (int q = 0; q < 4; ++q) kv[q] = zr;
#pragma unroll
  for (int kt = 0; kt < 4; ++kt) {
    bf16x8 af = *(const bf16x8*)(&lns[lr][kt * 32 + lg * 8]);
#pragma unroll
    for (int q = 0; q < 4; ++q) {
      bf16x8 bfr = *(const bf16x8*)(Wkv2 + (kt * 256 + (wave * 4 + q) * 16 + lr) * 32 + lg * 8);
      kv[q] = MFMA16(af, bfr, kv[q]);
    }
  }
#pragma unroll
  for (int q = 0; q < 4; ++q)
#pragma unroll
    for (int r = 0; r < 4; ++r) {
      int o2 = (wave * 4 + q) * 16 + lr;
      int mrow = lg * 4 + r;
      int pp = blk * 16 + mrow;
      int bb = pp >> 8, mm = pp & 255;
      float val = kv[q][r] + bkv[o2];
      unsigned short hv = f2bf(val);
      if (o2 < 128) {                       // K2: [(b*2+h)*2 + d>>5][m][d&31]
        int h = o2 >> 6, d = o2 & 63;
        K2[((size_t)((bb * 2 + h) * 2 + (d >> 5)) * 256 + mm) * 32 + (d & 31)] = hv;
      } else {                              // V2: [(b*2+h)*8 + m>>5][d][m&31]
        int o3 = o2 - 128, h = o3 >> 6, d = o3 & 63;
        V2[((size_t)((bb * 2 + h) * 8 + (mm >> 5)) * 64 + d) * 32 + (mm & 31)] = hv;
      }
    }
}

// ======== K3: fused Qproj + attention + out-proj, all-contiguous frag loads ==============
// grid (256 n-tiles of 64 rows, 8 batches), 256 thr, 52 KB LDS -> 3 blocks/CU.
__global__ __launch_bounds__(256, 3) void attn_kernel(
    const unsigned short* __restrict__ x2, const float* __restrict__ bq, const float* __restrict__ bp,
    const unsigned short* __restrict__ Wq2, const unsigned short* __restrict__ Wp2,
    const unsigned short* __restrict__ K2, const unsigned short* __restrict__ V2,
    float* __restrict__ out) {
  const int tid = threadIdx.x;
  const int wave = tid >> 6, l = tid & 63, lg = l >> 4, lr = l & 15;
  const int b = blockIdx.y;
  const int n0 = blockIdx.x * 64;

  __shared__ unsigned short Qs[64][136];    // 17408 B
  __shared__ unsigned short Ps[4][16][272]; // 34816 B; reused as O [64][136] later

  const f32x4 zr = {0.f, 0.f, 0.f, 0.f};

  // ---- Q projection (scale 1/8 folded in; exact in bf16) ----
  {
    const unsigned short* xbase = x2 + (size_t)b * 2097152 + (size_t)((n0 + wave * 16) >> 4) * 2048;
    bf16x8 af[4];
#pragma unroll
    for (int kt = 0; kt < 4; ++kt)
      af[kt] = *(const bf16x8*)(xbase + kt * 512 + lr * 32 + lg * 8);
    f32x4 qa[8];
#pragma unroll
    for (int ct = 0; ct < 8; ++ct) qa[ct] = zr;
#pragma unroll
    for (int kt = 0; kt < 4; ++kt) {
#pragma unroll
      for (int ct = 0; ct < 8; ++ct) {
        bf16x8 bfr = *(const bf16x8*)(Wq2 + (kt * 128 + ct * 16 + lr) * 32 + lg * 8);
        qa[ct] = MFMA16(af[kt], bfr, qa[ct]);
      }
    }
#pragma unroll
    for (int ct = 0; ct < 8; ++ct)
#pragma unroll
      for (int r = 0; r < 4; ++r) {
        int row = wave * 16 + lg * 4 + r;
        int col = ct * 16 + lr;
        Qs[row][col] = f2bf((qa[ct][r] + bq[col]) * 0.125f);
      }
  }
  __syncthreads();

  f32x4 oacc[2][4];
#pragma unroll
  for (int h2 = 0; h2 < 2; ++h2)
#pragma unroll
    for (int dt = 0; dt < 4; ++dt) oacc[h2][dt] = zr;

  for (int h = 0; h < 2; ++h) {
    // S^T = mfma(K, Q): lane owns n = lr, m = mt*16+lg*4+r. K-frags contiguous from K2.
    f32x4 sacc[16];
#pragma unroll
    for (int mt = 0; mt < 16; ++mt) sacc[mt] = zr;
#pragma unroll
    for (int d0 = 0; d0 < 64; d0 += 32) {
      const unsigned short* kbase = K2 + (size_t)((b * 2 + h) * 2 + (d0 >> 5)) * 8192;
      bf16x8 qf = *(const bf16x8*)(&Qs[wave * 16 + lr][h * 64 + d0 + lg * 8]);
#pragma unroll
      for (int mt = 0; mt < 16; ++mt) {
        bf16x8 kf = *(const bf16x8*)(kbase + (mt * 16 + lr) * 32 + lg * 8);
        sacc[mt] = MFMA16(kf, qf, sacc[mt]);
      }
    }
    // softmax over m=256 (Q pre-scaled)
    float mx = -1e30f;
#pragma unroll
    for (int mt = 0; mt < 16; ++mt)
#pragma unroll
      for (int r = 0; r < 4; ++r) mx = fmaxf(mx, sacc[mt][r]);
    mx = fmaxf(mx, __shfl_xor(mx, 16));
    mx = fmaxf(mx, __shfl_xor(mx, 32));
    float sum = 0.f;
#pragma unroll
    for (int mt = 0; mt < 16; ++mt)
#pragma unroll
      for (int r = 0; r < 4; ++r) {
        float pv = __expf(sacc[mt][r] - mx);
        sacc[mt][r] = pv; sum += pv;
      }
    sum += __shfl_xor(sum, 16);
    sum += __shfl_xor(sum, 32);
    float inv = 1.f / sum;
#pragma unroll
    for (int mt = 0; mt < 16; ++mt) {
      unsigned int w0 = (unsigned int)f2bf(sacc[mt][0] * inv) | ((unsigned int)f2bf(sacc[mt][1] * inv) << 16);
      unsigned int w1 = (unsigned int)f2bf(sacc[mt][2] * inv) | ((unsigned int)f2bf(sacc[mt][3] * inv) << 16);
      uint2 pw; pw.x = w0; pw.y = w1;
      *(uint2*)(&Ps[wave][lr][mt * 16 + lg * 4]) = pw;   // P[n_local=lr][m]
    }

    // PV: O[16 n][64 d] += P @ V_h  (V-frags contiguous from V2)
#pragma unroll
    for (int ki = 0; ki < 8; ++ki) {
      const unsigned short* vbase = V2 + (size_t)((b * 2 + h) * 8 + ki) * 2048;
      bf16x8 pf = *(const bf16x8*)(&Ps[wave][lr][ki * 32 + lg * 8]);
#pragma unroll
      for (int dt = 0; dt < 4; ++dt) {
        bf16x8 vf = *(const bf16x8*)(vbase + (dt * 16 + lr) * 32 + lg * 8);
        oacc[h][dt] = MFMA16(pf, vf, oacc[h][dt]);
      }
    }
  }  // head

  __syncthreads();
  unsigned short* Op = &Ps[0][0][0];  // [64][136]
#pragma unroll
  for (int h = 0; h < 2; ++h)
#pragma unroll
    for (int dt = 0; dt < 4; ++dt)
#pragma unroll
      for (int r = 0; r < 4; ++r) {
        int row = wave * 16 + lg * 4 + r;
        int col = h * 64 + dt * 16 + lr;
        Op[row * 136 + col] = f2bf(oacc[h][dt][r]);
      }

  f32x4 yacc[8];
#pragma unroll
  for (int ct = 0; ct < 8; ++ct) yacc[ct] = zr;
#pragma unroll
  for (int kt = 0; kt < 4; ++kt) {
    bf16x8 af = *(const bf16x8*)(&Op[(wave * 16 + lr) * 136 + kt * 32 + lg * 8]);
#pragma unroll
    for (int ct = 0; ct < 8; ++ct) {
      bf16x8 bfr = *(const bf16x8*)(Wp2 + (kt * 128 + ct * 16 + lr) * 32 + lg * 8);
      yacc[ct] = MFMA16(af, bfr, yacc[ct]);
    }
  }
#pragma unroll
  for (int ct = 0; ct < 8; ++ct)
#pragma unroll
    for (int r = 0; r < 4; ++r) {
      int n = n0 + wave * 16 + lg * 4 + r;
      int o = ct * 16 + lr;
      out[((size_t)(b * 16384 + n)) * 128 + o] = yacc[ct][r] + bp[o];
    }
}

extern "C" void kernel_launch(void* const* d_in, const int* in_sizes, int n_in,
                              void* d_out, int out_size, void* d_ws, size_t ws_size,
                              hipStream_t stream) {
  const float* x = (const float*)d_in[0];
  const float* Wq = (const float*)d_in[3];
  const float* bq = (const float*)d_in[4];
  const float* Wkv = (const float*)d_in[5];
  const float* bkv = (const float*)d_in[6];
  const float* Wp = (const float*)d_in[7];
  const float* bp = (const float*)d_in[8];
  const float* Wsr = (const float*)d_in[9];
  const float* bsr = (const float*)d_in[10];
  const float* gamma = (const float*)d_in[11];
  const float* beta = (const float*)d_in[12];
  float* out = (float*)d_out;

  unsigned short* ws = (unsigned short*)d_ws;
  unsigned short* Wq2 = ws;                   // 16384
  unsigned short* Wp2 = ws + 16384;           // 16384
  unsigned short* Wkv2 = ws + 32768;          // 32768
  unsigned short* W2sr = ws + 65536;          // 1048576
  unsigned short* K2 = ws + 1114112;          // 262144
  unsigned short* V2 = ws + 1376256;          // 262144
  unsigned short* x2 = ws + 1638400;          // 16777216
  unsigned short* x3 = ws + 18415616;         // 16777216
  float* scratch = (float*)(ws + 35192832);   // 4 MB f32 partials

  xcast_prep_kernel<<<8512, 256, 0, stream>>>(x, Wq, Wkv, Wp, Wsr, x2, x3, Wq2, Wkv2, Wp2, W2sr);
  conv_split_kernel<<<dim3(128, 4), 256, 0, stream>>>(x3, W2sr, scratch);
  ln_kv_kernel<<<128, 256, 0, stream>>>(scratch, bsr, gamma, beta, Wkv2, bkv, K2, V2);
  attn_kernel<<<dim3(256, 8), 256, 0, stream>>>(x2, bq, bp, Wq2, Wp2, K2, V2, out);
}